// Round 2
// baseline (700.305 us; speedup 1.0000x reference)
//
#include <hip/hip_runtime.h>

#define T_STEPS 2048
#define SEQS_PER_BLOCK 16

// ---- guaranteed-native transcendentals (v_exp_f32 / v_rcp_f32) -------------
__device__ __forceinline__ float fast_rcp(float x) {
    return __builtin_amdgcn_rcpf(x);
}

// sigmoid(x) = 1/(1+e^{-x});  e^{-x} = exp2(x * -log2(e))
__device__ __forceinline__ float fsigmoid(float x) {
    float e = __builtin_amdgcn_exp2f(x * -1.4426950408889634f);
    return fast_rcp(1.0f + e);
}

// tanh(x) = 1 - 2/(e^{2x}+1);  e^{2x} = exp2(x * 2*log2(e))
// saturates correctly: x->+inf: e=inf -> 1; x->-inf: e=0 -> -1. NaN-free.
__device__ __forceinline__ float ftanh_fast(float x) {
    float e = __builtin_amdgcn_exp2f(x * 2.8853900817779268f);
    return fmaf(-2.0f, fast_rcp(e + 1.0f), 1.0f);
}

// ---- DPP rotation all-reduce within a 16-lane row --------------------------
// row_ror:r = 0x120|r. After +ror1,+ror2,+ror4,+ror8 every lane of the row
// holds the 16-lane sum (rotation-composition all-reduce). DPP is VALU-rate:
// ~4 cyc/stage vs ~25-30 cyc for ds_swizzle-based __shfl_xor.
template<int CTRL>
__device__ __forceinline__ float dpp_ror_add(float v) {
    int t = __builtin_amdgcn_update_dpp(0, __float_as_int(v), CTRL, 0xF, 0xF, true);
    return v + __int_as_float(t);
}
__device__ __forceinline__ float row16_allreduce(float v) {
    v = dpp_ror_add<0x121>(v);  // ror 1
    v = dpp_ror_add<0x122>(v);  // ror 2
    v = dpp_ror_add<0x124>(v);  // ror 4
    v = dpp_ror_add<0x128>(v);  // ror 8
    return v;
}

extern "C" __global__ __launch_bounds__(256) void lstm_seq_kernel(
    const float* __restrict__ u,    // (B, T, 4): x0 x1 y0 y1
    const float* __restrict__ Wih,  // (64, 2)
    const float* __restrict__ Whh,  // (64, 2)
    const float* __restrict__ bih,  // (64,)
    const float* __restrict__ bhh,  // (64,)
    const float* __restrict__ Whr,  // (2, 16)
    const int* __restrict__ ncp,    // n_context scalar
    float* __restrict__ out,        // (B, T, 2)
    int B)
{
    const int lane = threadIdx.x & 15;   // hidden unit owned by this lane
    const int grp  = threadIdx.x >> 4;   // sequence within block
    const int seq  = blockIdx.x * SEQS_PER_BLOCK + grp;
    if (seq >= B) return;

    const int nc = *ncp;   // 1024; assumed multiple of 16 (output-buffer chunking)

    // per-lane weights: rows lane (i), lane+16 (f), lane+32 (g), lane+48 (o)
    const int ri = lane, rf = lane + 16, rg = lane + 32, ro = lane + 48;
    const float2 wih_i = ((const float2*)Wih)[ri];
    const float2 wih_f = ((const float2*)Wih)[rf];
    const float2 wih_g = ((const float2*)Wih)[rg];
    const float2 wih_o = ((const float2*)Wih)[ro];
    const float2 whh_i = ((const float2*)Whh)[ri];
    const float2 whh_f = ((const float2*)Whh)[rf];
    const float2 whh_g = ((const float2*)Whh)[rg];
    const float2 whh_o = ((const float2*)Whh)[ro];
    const float bi = bih[ri] + bhh[ri];
    const float bf = bih[rf] + bhh[rf];
    const float bg = bih[rg] + bhh[rg];
    const float bo = bih[ro] + bhh[ro];
    const float whr0 = Whr[lane];        // W_hr[0][lane]
    const float whr1 = Whr[16 + lane];   // W_hr[1][lane]

    const float* up = u + (size_t)seq * T_STEPS * 4;
    float*       op = out + (size_t)seq * T_STEPS * 2;

    float c  = 0.0f;
    float h0 = 0.0f, h1 = 0.0f;    // fed-back h (phase 2)
    float bh0 = 0.0f, bh1 = 0.0f;  // per-lane output buffer (16-step chunks)

    // prefetch step 0 input (all 16 lanes of the group load the same float4)
    float4 u4 = ((const float4*)up)[0];

    // ---------------- phase 1: teacher-forced (h injected from u4.zw) --------
    #pragma unroll 16
    for (int t = 0; t < nc; ++t) {
        const float4 cur = u4;
        const int tn = (t + 1 < T_STEPS) ? (t + 1) : t;
        u4 = ((const float4*)up)[tn];   // prefetch next step

        const float x0 = cur.x, x1 = cur.y;
        const float hh0 = cur.z, hh1 = cur.w;   // injected h

        float pi = fmaf(x0, wih_i.x, fmaf(x1, wih_i.y, fmaf(hh0, whh_i.x, fmaf(hh1, whh_i.y, bi))));
        float pf = fmaf(x0, wih_f.x, fmaf(x1, wih_f.y, fmaf(hh0, whh_f.x, fmaf(hh1, whh_f.y, bf))));
        float pg = fmaf(x0, wih_g.x, fmaf(x1, wih_g.y, fmaf(hh0, whh_g.x, fmaf(hh1, whh_g.y, bg))));
        float po = fmaf(x0, wih_o.x, fmaf(x1, wih_o.y, fmaf(hh0, whh_o.x, fmaf(hh1, whh_o.y, bo))));

        const float si = fsigmoid(pi);
        const float sf = fsigmoid(pf);
        const float so = fsigmoid(po);
        const float tg = ftanh_fast(pg);

        c = fmaf(sf, c, si * tg);
        const float m = so * ftanh_fast(c);

        // project: h = (sum_j m_j*Whr[0][j], sum_j m_j*Whr[1][j]) via DPP allreduce
        h0 = row16_allreduce(m * whr0);
        h1 = row16_allreduce(m * whr1);

        // buffer output: lane s keeps step (chunk_base + s)'s h
        const int s = t & 15;
        bh0 = (s == lane) ? h0 : bh0;
        bh1 = (s == lane) ? h1 : bh1;
        if (s == 15) {
            ((float2*)(op + 2 * (t - 15)))[lane] = make_float2(bh0, bh1);
        }
    }

    // ---------------- phase 2: free-running (h fed back) ---------------------
    #pragma unroll 16
    for (int t = nc; t < T_STEPS; ++t) {
        const float4 cur = u4;
        const int tn = (t + 1 < T_STEPS) ? (t + 1) : t;
        u4 = ((const float4*)up)[tn];

        const float x0 = cur.x, x1 = cur.y;
        const float hh0 = h0, hh1 = h1;   // fed-back h

        float pi = fmaf(x0, wih_i.x, fmaf(x1, wih_i.y, fmaf(hh0, whh_i.x, fmaf(hh1, whh_i.y, bi))));
        float pf = fmaf(x0, wih_f.x, fmaf(x1, wih_f.y, fmaf(hh0, whh_f.x, fmaf(hh1, whh_f.y, bf))));
        float pg = fmaf(x0, wih_g.x, fmaf(x1, wih_g.y, fmaf(hh0, whh_g.x, fmaf(hh1, whh_g.y, bg))));
        float po = fmaf(x0, wih_o.x, fmaf(x1, wih_o.y, fmaf(hh0, whh_o.x, fmaf(hh1, whh_o.y, bo))));

        const float si = fsigmoid(pi);
        const float sf = fsigmoid(pf);
        const float so = fsigmoid(po);
        const float tg = ftanh_fast(pg);

        c = fmaf(sf, c, si * tg);
        const float m = so * ftanh_fast(c);

        h0 = row16_allreduce(m * whr0);
        h1 = row16_allreduce(m * whr1);

        const int s = t & 15;
        bh0 = (s == lane) ? h0 : bh0;
        bh1 = (s == lane) ? h1 : bh1;
        if (s == 15) {
            ((float2*)(op + 2 * (t - 15)))[lane] = make_float2(bh0, bh1);
        }
    }
}

extern "C" void kernel_launch(void* const* d_in, const int* in_sizes, int n_in,
                              void* d_out, int out_size, void* d_ws, size_t ws_size,
                              hipStream_t stream) {
    const float* u   = (const float*)d_in[0];
    const float* Wih = (const float*)d_in[1];
    const float* Whh = (const float*)d_in[2];
    const float* bih = (const float*)d_in[3];
    const float* bhh = (const float*)d_in[4];
    const float* Whr = (const float*)d_in[5];
    const int*   ncp = (const int*)d_in[6];
    float* out = (float*)d_out;

    const int B = in_sizes[0] / (T_STEPS * 4);  // u_train is (B, T, 4)
    const int blocks = (B + SEQS_PER_BLOCK - 1) / SEQS_PER_BLOCK;

    hipLaunchKernelGGL(lstm_seq_kernel, dim3(blocks), dim3(256), 0, stream,
                       u, Wih, Whh, bih, bhh, Whr, ncp, out, B);
}

// Round 8
// 671.730 us; speedup vs baseline: 1.0425x; 1.0425x over previous
//
#include <hip/hip_runtime.h>

#define T_STEPS 2048
#define SEQS_PER_BLOCK 8   // 32 lanes per sequence, block = 256 threads

// ---- native transcendentals ------------------------------------------------
__device__ __forceinline__ float fast_rcp(float x) { return __builtin_amdgcn_rcpf(x); }
__device__ __forceinline__ float fast_exp2(float x) { return __builtin_amdgcn_exp2f(x); }

#define LOG2E   1.4426950408889634f
#define LOG2E2  2.8853900817779268f

// ---- DPP rotation all-reduce within each 16-lane row (HW-verified r2) ------
template<int CTRL>
__device__ __forceinline__ float dpp_ror_add(float v) {
    int t = __builtin_amdgcn_update_dpp(0, __float_as_int(v), CTRL, 0xF, 0xF, true);
    return v + __int_as_float(t);
}
__device__ __forceinline__ float row16_allreduce(float v) {
    v = dpp_ror_add<0x121>(v);  // ror 1
    v = dpp_ror_add<0x122>(v);  // ror 2
    v = dpp_ror_add<0x124>(v);  // ror 4
    v = dpp_ror_add<0x128>(v);  // ror 8
    return v;
}

// ---- xor-16 lane swap within each 32-lane group (BitMode: xor<<10 | 0x1F) --
__device__ __forceinline__ float swz_xor16(float v) {
    return __int_as_float(__builtin_amdgcn_ds_swizzle(__float_as_int(v), 0x401F));
}

extern "C" __global__ __launch_bounds__(256) void lstm_seq_kernel(
    const float* __restrict__ u,    // (B, T, 4): x0 x1 y0 y1
    const float* __restrict__ Wih,  // (64, 2)
    const float* __restrict__ Whh,  // (64, 2)
    const float* __restrict__ bih,  // (64,)
    const float* __restrict__ bhh,  // (64,)
    const float* __restrict__ Whr,  // (2, 16)
    const int* __restrict__ ncp,    // n_context scalar (1024)
    float* __restrict__ out,        // (B, T, 2)
    int B)
{
    const int l    = threadIdx.x & 31;   // lane within sequence group
    const int u16  = l & 15;             // hidden unit owned
    const int half = l >> 4;             // 0: rows {i,g}; 1: rows {f,o}
    const int grp  = threadIdx.x >> 5;   // sequence within block
    const int seq  = blockIdx.x * SEQS_PER_BLOCK + grp;
    if (seq >= B) return;

    const int nc = *ncp;                 // 1024 (multiple of 4 assumed)

    // rows: A = i (half0) / f (half1);  B = g (half0) / o (half1)
    const int rowA = u16 + (half << 4);
    const int rowB = u16 + 32 + (half << 4);

    const float2 wihA = ((const float2*)Wih)[rowA];
    const float2 wihB = ((const float2*)Wih)[rowB];
    const float2 whhA = ((const float2*)Whh)[rowA];
    const float2 whhB = ((const float2*)Whh)[rowB];
    const float  bA   = bih[rowA] + bhh[rowA];
    const float  bB   = bih[rowB] + bhh[rowB];
    // B-activation: half0 -> tanh (k=-2log2e, a=2, b=-1); half1 -> sigmoid
    const float  kB   = half ? -LOG2E : -LOG2E2;
    const float  aB   = half ? 1.0f : 2.0f;
    const float  cBc  = half ? 0.0f : -1.0f;
    const float  whr0 = Whr[u16];        // W_hr[0][u]
    const float  whr1 = Whr[16 + u16];   // W_hr[1][u]

    const float*  up  = u + (size_t)seq * T_STEPS * 4;
    const float4* upv = (const float4*)up;
    float*        op  = out + (size_t)seq * T_STEPS * 2;

    float c  = 0.0f;
    float h0 = 0.0f, h1 = 0.0f;    // fed-back / emitted h
    float bh0 = 0.0f, bh1 = 0.0f;  // per-lane output buffer (16-step chunks)

    // one LSTM step; `injected` is constant at each call site (folds on inline)
    auto step = [&](const float4 cur, int t, bool injected) {
        const float x0 = cur.x, x1 = cur.y;
        const float hh0 = injected ? cur.z : h0;
        const float hh1 = injected ? cur.w : h1;

        float pA = fmaf(x0, wihA.x, fmaf(x1, wihA.y, fmaf(hh0, whhA.x, fmaf(hh1, whhA.y, bA))));
        float pB = fmaf(x0, wihB.x, fmaf(x1, wihB.y, fmaf(hh0, whhB.x, fmaf(hh1, whhB.y, bB))));

        // A rows (i,f) are always sigmoid; B rows: tanh (g) or sigmoid (o)
        float sA = fast_rcp(1.0f + fast_exp2(pA * -LOG2E));
        float sB = fmaf(aB, fast_rcp(1.0f + fast_exp2(pB * kB)), cBc);

        // swap halves: gives each lane the other half's activations
        float swA = swz_xor16(sA);
        float swB = swz_xor16(sB);
        const float si = half ? swA : sA;
        const float sf = half ? sA  : swA;
        const float tg = half ? swB : sB;
        const float so = half ? sB  : swB;

        c = fmaf(sf, c, si * tg);                 // identical on both halves
        float th = fmaf(2.0f, fast_rcp(1.0f + fast_exp2(c * -LOG2E2)), -1.0f);
        float m  = so * th;                       // m_u on every lane

        h0 = row16_allreduce(m * whr0);           // h on all 32 lanes
        h1 = row16_allreduce(m * whr1);

        // buffer outputs on half-0 lanes; one coalesced 128B store / 16 steps
        const int  s    = t & 15;
        const bool keep = (half == 0) & (u16 == s);
        bh0 = keep ? h0 : bh0;
        bh1 = keep ? h1 : bh1;
        if (s == 15 && half == 0) {
            ((float2*)(op + 2 * (t - 15)))[u16] = make_float2(bh0, bh1);
        }
    };

    // 4-step (one 64B line) deep prefetch
    float4 q0 = upv[0], q1 = upv[1], q2 = upv[2], q3 = upv[3];
    int tb = 0;

    // ---------------- phase 1: teacher-forced --------------------------------
    // nc is a multiple of 4 and < T_STEPS-4, so prefetch indices need no clamp
    #pragma unroll 2
    for (; tb < nc; tb += 4) {
        const int nb = tb + 4;
        float4 n0 = upv[nb];
        float4 n1 = upv[nb + 1];
        float4 n2 = upv[nb + 2];
        float4 n3 = upv[nb + 3];
        step(q0, tb,     true);
        step(q1, tb + 1, true);
        step(q2, tb + 2, true);
        step(q3, tb + 3, true);
        q0 = n0; q1 = n1; q2 = n2; q3 = n3;
    }

    // ---------------- phase 2: free-running ----------------------------------
    // last iteration prefetches line tb+4 == T_STEPS: clamp once per block of 4
    #pragma unroll 2
    for (; tb < T_STEPS; tb += 4) {
        const int nb = (tb + 4 < T_STEPS) ? tb + 4 : T_STEPS - 4;
        float4 n0 = upv[nb];
        float4 n1 = upv[nb + 1];
        float4 n2 = upv[nb + 2];
        float4 n3 = upv[nb + 3];
        step(q0, tb,     false);
        step(q1, tb + 1, false);
        step(q2, tb + 2, false);
        step(q3, tb + 3, false);
        q0 = n0; q1 = n1; q2 = n2; q3 = n3;
    }
}

extern "C" void kernel_launch(void* const* d_in, const int* in_sizes, int n_in,
                              void* d_out, int out_size, void* d_ws, size_t ws_size,
                              hipStream_t stream) {
    const float* u   = (const float*)d_in[0];
    const float* Wih = (const float*)d_in[1];
    const float* Whh = (const float*)d_in[2];
    const float* bih = (const float*)d_in[3];
    const float* bhh = (const float*)d_in[4];
    const float* Whr = (const float*)d_in[5];
    const int*   ncp = (const int*)d_in[6];
    float* out = (float*)d_out;

    const int B = in_sizes[0] / (T_STEPS * 4);  // u_train is (B, T, 4)
    const int blocks = (B + SEQS_PER_BLOCK - 1) / SEQS_PER_BLOCK;

    hipLaunchKernelGGL(lstm_seq_kernel, dim3(blocks), dim3(256), 0, stream,
                       u, Wih, Whh, bih, bhh, Whr, ncp, out, B);
}

// Round 10
// 631.473 us; speedup vs baseline: 1.1090x; 1.0638x over previous
//
#include <hip/hip_runtime.h>

#define T_STEPS 2048
#define SEQS_PER_BLOCK 16   // 16 lanes per sequence, block = 256 threads

// ---- native transcendentals ------------------------------------------------
__device__ __forceinline__ float fast_rcp(float x) { return __builtin_amdgcn_rcpf(x); }
__device__ __forceinline__ float fast_exp2(float x) { return __builtin_amdgcn_exp2f(x); }

#define LOG2E   1.4426950408889634f
#define LOG2E2  2.8853900817779268f

// sigmoid(x) = rcp(1 + exp2(-x*log2e))
__device__ __forceinline__ float fsigmoid(float x) {
    return fast_rcp(1.0f + fast_exp2(x * -LOG2E));
}
// tanh(x) = 1 - 2*rcp(1 + exp2(x*2log2e));  saturates correctly, NaN-free
__device__ __forceinline__ float ftanh_fast(float x) {
    return fmaf(-2.0f, fast_rcp(1.0f + fast_exp2(x * LOG2E2)), 1.0f);
}

// ---- DPP rotation all-reduce within each 16-lane row (HW-verified r8) ------
// After +ror1,+ror2,+ror4,+ror8 every lane of the row holds the 16-lane sum.
// Pure VALU rate: no LDS pipe, no lgkmcnt — keeps the recurrence chain short.
template<int CTRL>
__device__ __forceinline__ float dpp_ror_add(float v) {
    int t = __builtin_amdgcn_update_dpp(0, __float_as_int(v), CTRL, 0xF, 0xF, true);
    return v + __int_as_float(t);
}
__device__ __forceinline__ float row16_allreduce(float v) {
    v = dpp_ror_add<0x121>(v);  // row_ror:1
    v = dpp_ror_add<0x122>(v);  // row_ror:2
    v = dpp_ror_add<0x124>(v);  // row_ror:4
    v = dpp_ror_add<0x128>(v);  // row_ror:8
    return v;
}

extern "C" __global__ __launch_bounds__(256) void lstm_seq_kernel(
    const float* __restrict__ u,    // (B, T, 4): x0 x1 y0 y1
    const float* __restrict__ Wih,  // (64, 2)
    const float* __restrict__ Whh,  // (64, 2)
    const float* __restrict__ bih,  // (64,)
    const float* __restrict__ bhh,  // (64,)
    const float* __restrict__ Whr,  // (2, 16)
    const int* __restrict__ ncp,    // n_context scalar (1024)
    float* __restrict__ out,        // (B, T, 2)
    int B)
{
    const int lane = threadIdx.x & 15;   // hidden unit owned by this lane
    const int grp  = threadIdx.x >> 4;   // sequence within block
    const int seq  = blockIdx.x * SEQS_PER_BLOCK + grp;
    if (seq >= B) return;

    const int nc = *ncp;                 // 1024 (multiple of 4; < T_STEPS-4)

    // per-lane weights: rows lane (i), lane+16 (f), lane+32 (g), lane+48 (o)
    const int ri = lane, rf = lane + 16, rg = lane + 32, ro = lane + 48;
    const float2 wih_i = ((const float2*)Wih)[ri];
    const float2 wih_f = ((const float2*)Wih)[rf];
    const float2 wih_g = ((const float2*)Wih)[rg];
    const float2 wih_o = ((const float2*)Wih)[ro];
    const float2 whh_i = ((const float2*)Whh)[ri];
    const float2 whh_f = ((const float2*)Whh)[rf];
    const float2 whh_g = ((const float2*)Whh)[rg];
    const float2 whh_o = ((const float2*)Whh)[ro];
    const float bi = bih[ri] + bhh[ri];
    const float bf = bih[rf] + bhh[rf];
    const float bg = bih[rg] + bhh[rg];
    const float bo = bih[ro] + bhh[ro];
    const float whr0 = Whr[lane];        // W_hr[0][lane]
    const float whr1 = Whr[16 + lane];   // W_hr[1][lane]

    const float*  up  = u + (size_t)seq * T_STEPS * 4;
    const float4* upv = (const float4*)up;
    float*        op  = out + (size_t)seq * T_STEPS * 2;

    float c  = 0.0f;
    float h0 = 0.0f, h1 = 0.0f;    // fed-back / emitted h
    float bh0 = 0.0f, bh1 = 0.0f;  // per-lane output buffer (16-step chunks)

    // one LSTM step; `injected` is a compile-time-constant at each call site
    auto step = [&](const float4 cur, int t, bool injected) {
        const float x0 = cur.x, x1 = cur.y;
        const float hh0 = injected ? cur.z : h0;
        const float hh1 = injected ? cur.w : h1;

        // gates: chain from h is only 2 dependent FMAs (x-part has full ILP)
        float pi = fmaf(hh0, whh_i.x, fmaf(hh1, whh_i.y, fmaf(x0, wih_i.x, fmaf(x1, wih_i.y, bi))));
        float pf = fmaf(hh0, whh_f.x, fmaf(hh1, whh_f.y, fmaf(x0, wih_f.x, fmaf(x1, wih_f.y, bf))));
        float pg = fmaf(hh0, whh_g.x, fmaf(hh1, whh_g.y, fmaf(x0, wih_g.x, fmaf(x1, wih_g.y, bg))));
        float po = fmaf(hh0, whh_o.x, fmaf(hh1, whh_o.y, fmaf(x0, wih_o.x, fmaf(x1, wih_o.y, bo))));

        // 4 independent activations (ILP covers transcendental latency)
        const float si = fsigmoid(pi);
        const float sf = fsigmoid(pf);
        const float so = fsigmoid(po);
        const float tg = ftanh_fast(pg);

        c = fmaf(sf, c, si * tg);
        const float m = so * ftanh_fast(c);

        // h = (m . Whr[0], m . Whr[1]) — pure-VALU DPP allreduce, h on all lanes
        h0 = row16_allreduce(m * whr0);
        h1 = row16_allreduce(m * whr1);

        // lane s buffers step (base+s)'s h; one coalesced 128B store / 16 steps
        const int s = t & 15;
        bh0 = (s == lane) ? h0 : bh0;
        bh1 = (s == lane) ? h1 : bh1;
        if (s == 15) {
            ((float2*)(op + 2 * (t - 15)))[lane] = make_float2(bh0, bh1);
        }
    };

    // 4-step (one 64B line) deep prefetch
    float4 q0 = upv[0], q1 = upv[1], q2 = upv[2], q3 = upv[3];
    int tb = 0;

    // ---------------- phase 1: teacher-forced --------------------------------
    // nc multiple of 4 and < T_STEPS-4: prefetch indices need no clamp
    #pragma unroll 2
    for (; tb < nc; tb += 4) {
        const int nb = tb + 4;
        float4 n0 = upv[nb];
        float4 n1 = upv[nb + 1];
        float4 n2 = upv[nb + 2];
        float4 n3 = upv[nb + 3];
        step(q0, tb,     true);
        step(q1, tb + 1, true);
        step(q2, tb + 2, true);
        step(q3, tb + 3, true);
        q0 = n0; q1 = n1; q2 = n2; q3 = n3;
    }

    // ---------------- phase 2: free-running ----------------------------------
    // final iteration would prefetch line T_STEPS: clamp (values dead)
    #pragma unroll 2
    for (; tb < T_STEPS; tb += 4) {
        const int nb = (tb + 4 < T_STEPS) ? tb + 4 : T_STEPS - 4;
        float4 n0 = upv[nb];
        float4 n1 = upv[nb + 1];
        float4 n2 = upv[nb + 2];
        float4 n3 = upv[nb + 3];
        step(q0, tb,     false);
        step(q1, tb + 1, false);
        step(q2, tb + 2, false);
        step(q3, tb + 3, false);
        q0 = n0; q1 = n1; q2 = n2; q3 = n3;
    }
}

extern "C" void kernel_launch(void* const* d_in, const int* in_sizes, int n_in,
                              void* d_out, int out_size, void* d_ws, size_t ws_size,
                              hipStream_t stream) {
    const float* u   = (const float*)d_in[0];
    const float* Wih = (const float*)d_in[1];
    const float* Whh = (const float*)d_in[2];
    const float* bih = (const float*)d_in[3];
    const float* bhh = (const float*)d_in[4];
    const float* Whr = (const float*)d_in[5];
    const int*   ncp = (const int*)d_in[6];
    float* out = (float*)d_out;

    const int B = in_sizes[0] / (T_STEPS * 4);  // u_train is (B, T, 4)
    const int blocks = (B + SEQS_PER_BLOCK - 1) / SEQS_PER_BLOCK;

    hipLaunchKernelGGL(lstm_seq_kernel, dim3(blocks), dim3(256), 0, stream,
                       u, Wih, Whh, bih, bhh, Whr, ncp, out, B);
}

// Round 11
// 532.685 us; speedup vs baseline: 1.3147x; 1.1855x over previous
//
#include <hip/hip_runtime.h>

#define T_STEPS 2048
#define SEQS_PER_BLOCK 16   // 16 lanes per sequence, block = 256 threads

// ---- native transcendentals ------------------------------------------------
__device__ __forceinline__ float fast_rcp(float x) { return __builtin_amdgcn_rcpf(x); }
__device__ __forceinline__ float fast_exp2(float x) { return __builtin_amdgcn_exp2f(x); }

#define LOG2E   1.4426950408889634f
#define LOG2E2  2.8853900817779268f

// sigmoid(x) = rcp(1 + exp2(-x*log2e))   (identical numerics to r10)
__device__ __forceinline__ float fsigmoid(float x) {
    return fast_rcp(1.0f + fast_exp2(x * -LOG2E));
}
// tanh(x) = 1 - 2*rcp(1 + exp2(x*2log2e));  saturates correctly, NaN-free
__device__ __forceinline__ float ftanh_fast(float x) {
    return fmaf(-2.0f, fast_rcp(1.0f + fast_exp2(x * LOG2E2)), 1.0f);
}

// ---- DPP rotation all-reduce within each 16-lane row (HW-verified r8/r10) --
template<int CTRL>
__device__ __forceinline__ float dpp_ror_add(float v) {
    int t = __builtin_amdgcn_update_dpp(0, __float_as_int(v), CTRL, 0xF, 0xF, true);
    return v + __int_as_float(t);
}
__device__ __forceinline__ float row16_allreduce(float v) {
    v = dpp_ror_add<0x121>(v);  // row_ror:1
    v = dpp_ror_add<0x122>(v);  // row_ror:2
    v = dpp_ror_add<0x124>(v);  // row_ror:4
    v = dpp_ror_add<0x128>(v);  // row_ror:8
    return v;
}

// ---- shared per-lane weight bundle -----------------------------------------
struct LaneW {
    float2 wih_i, wih_f, wih_g, wih_o;
    float2 whh_i, whh_f, whh_g, whh_o;
    float  bi, bf, bg, bo;
    float  whr0, whr1;
};

__device__ __forceinline__ LaneW load_lane_weights(
    const float* __restrict__ Wih, const float* __restrict__ Whh,
    const float* __restrict__ bih, const float* __restrict__ bhh,
    const float* __restrict__ Whr, int lane)
{
    LaneW w;
    const int ri = lane, rf = lane + 16, rg = lane + 32, ro = lane + 48;
    w.wih_i = ((const float2*)Wih)[ri];  w.wih_f = ((const float2*)Wih)[rf];
    w.wih_g = ((const float2*)Wih)[rg];  w.wih_o = ((const float2*)Wih)[ro];
    w.whh_i = ((const float2*)Whh)[ri];  w.whh_f = ((const float2*)Whh)[rf];
    w.whh_g = ((const float2*)Whh)[rg];  w.whh_o = ((const float2*)Whh)[ro];
    w.bi = bih[ri] + bhh[ri];  w.bf = bih[rf] + bhh[rf];
    w.bg = bih[rg] + bhh[rg];  w.bo = bih[ro] + bhh[ro];
    w.whr0 = Whr[lane];  w.whr1 = Whr[16 + lane];
    return w;
}

// =========================== phase 1: teacher-forced ========================
// chain = single c-FMA per step; h injected from input. Writes y[0..nc) and
// hands off (c, h) at t = nc-1 via workspace.
extern "C" __global__ __launch_bounds__(256) void lstm_phase1_kernel(
    const float* __restrict__ u, const float* __restrict__ Wih,
    const float* __restrict__ Whh, const float* __restrict__ bih,
    const float* __restrict__ bhh, const float* __restrict__ Whr,
    const int* __restrict__ ncp, float* __restrict__ out,
    float* __restrict__ ws_c, float* __restrict__ ws_h, int B)
{
    const int lane = threadIdx.x & 15;
    const int grp  = threadIdx.x >> 4;
    const int seq  = blockIdx.x * SEQS_PER_BLOCK + grp;
    if (seq >= B) return;

    const int nc = *ncp;   // 1024: multiple of 16, < T_STEPS-4

    const LaneW w = load_lane_weights(Wih, Whh, bih, bhh, Whr, lane);

    const float4* upv = (const float4*)(u + (size_t)seq * T_STEPS * 4);
    float*        op  = out + (size_t)seq * T_STEPS * 2;

    float c = 0.0f;
    float h0 = 0.0f, h1 = 0.0f;
    float bh0 = 0.0f, bh1 = 0.0f;

    auto step = [&](const float4 cur, int t) {
        const float x0 = cur.x, x1 = cur.y;
        const float hh0 = cur.z, hh1 = cur.w;   // injected h

        float pi = fmaf(hh0, w.whh_i.x, fmaf(hh1, w.whh_i.y, fmaf(x0, w.wih_i.x, fmaf(x1, w.wih_i.y, w.bi))));
        float pf = fmaf(hh0, w.whh_f.x, fmaf(hh1, w.whh_f.y, fmaf(x0, w.wih_f.x, fmaf(x1, w.wih_f.y, w.bf))));
        float pg = fmaf(hh0, w.whh_g.x, fmaf(hh1, w.whh_g.y, fmaf(x0, w.wih_g.x, fmaf(x1, w.wih_g.y, w.bg))));
        float po = fmaf(hh0, w.whh_o.x, fmaf(hh1, w.whh_o.y, fmaf(x0, w.wih_o.x, fmaf(x1, w.wih_o.y, w.bo))));

        const float si = fsigmoid(pi);
        const float sf = fsigmoid(pf);
        const float so = fsigmoid(po);
        const float tg = ftanh_fast(pg);

        c = fmaf(sf, c, si * tg);
        const float m = so * ftanh_fast(c);

        h0 = row16_allreduce(m * w.whr0);
        h1 = row16_allreduce(m * w.whr1);

        const int s = t & 15;
        bh0 = (s == lane) ? h0 : bh0;
        bh1 = (s == lane) ? h1 : bh1;
        if (s == 15) {
            ((float2*)(op + 2 * (t - 15)))[lane] = make_float2(bh0, bh1);
        }
    };

    float4 q0 = upv[0], q1 = upv[1], q2 = upv[2], q3 = upv[3];
    #pragma unroll 2
    for (int tb = 0; tb < nc; tb += 4) {
        const int nb = tb + 4;   // nb <= nc < T_STEPS: no clamp needed
        float4 n0 = upv[nb];
        float4 n1 = upv[nb + 1];
        float4 n2 = upv[nb + 2];
        float4 n3 = upv[nb + 3];
        step(q0, tb);
        step(q1, tb + 1);
        step(q2, tb + 2);
        step(q3, tb + 3);
        q0 = n0; q1 = n1; q2 = n2; q3 = n3;
    }

    // ---- handoff: c per (seq,unit); h per seq (identical on all lanes) -----
    ws_c[(size_t)seq * 16 + lane] = c;
    if (lane == 0) {
        ((float2*)ws_h)[seq] = make_float2(h0, h1);
    }
}

// =========================== phase 2: free-running ==========================
// h fed back through the DPP allreduce; starts from the phase-1 handoff.
extern "C" __global__ __launch_bounds__(256) void lstm_phase2_kernel(
    const float* __restrict__ u, const float* __restrict__ Wih,
    const float* __restrict__ Whh, const float* __restrict__ bih,
    const float* __restrict__ bhh, const float* __restrict__ Whr,
    const int* __restrict__ ncp, float* __restrict__ out,
    const float* __restrict__ ws_c, const float* __restrict__ ws_h, int B)
{
    const int lane = threadIdx.x & 15;
    const int grp  = threadIdx.x >> 4;
    const int seq  = blockIdx.x * SEQS_PER_BLOCK + grp;
    if (seq >= B) return;

    const int nc = *ncp;

    const LaneW w = load_lane_weights(Wih, Whh, bih, bhh, Whr, lane);

    const float4* upv = (const float4*)(u + (size_t)seq * T_STEPS * 4);
    float*        op  = out + (size_t)seq * T_STEPS * 2;

    float c = ws_c[(size_t)seq * 16 + lane];
    const float2 hh = ((const float2*)ws_h)[seq];
    float h0 = hh.x, h1 = hh.y;
    float bh0 = 0.0f, bh1 = 0.0f;

    auto step = [&](const float4 cur, int t) {
        const float x0 = cur.x, x1 = cur.y;
        const float hh0 = h0, hh1 = h1;         // fed-back h

        float pi = fmaf(hh0, w.whh_i.x, fmaf(hh1, w.whh_i.y, fmaf(x0, w.wih_i.x, fmaf(x1, w.wih_i.y, w.bi))));
        float pf = fmaf(hh0, w.whh_f.x, fmaf(hh1, w.whh_f.y, fmaf(x0, w.wih_f.x, fmaf(x1, w.wih_f.y, w.bf))));
        float pg = fmaf(hh0, w.whh_g.x, fmaf(hh1, w.whh_g.y, fmaf(x0, w.wih_g.x, fmaf(x1, w.wih_g.y, w.bg))));
        float po = fmaf(hh0, w.whh_o.x, fmaf(hh1, w.whh_o.y, fmaf(x0, w.wih_o.x, fmaf(x1, w.wih_o.y, w.bo))));

        const float si = fsigmoid(pi);
        const float sf = fsigmoid(pf);
        const float so = fsigmoid(po);
        const float tg = ftanh_fast(pg);

        c = fmaf(sf, c, si * tg);
        const float m = so * ftanh_fast(c);

        h0 = row16_allreduce(m * w.whr0);
        h1 = row16_allreduce(m * w.whr1);

        const int s = t & 15;
        bh0 = (s == lane) ? h0 : bh0;
        bh1 = (s == lane) ? h1 : bh1;
        if (s == 15) {
            ((float2*)(op + 2 * (t - 15)))[lane] = make_float2(bh0, bh1);
        }
    };

    float4 q0 = upv[nc], q1 = upv[nc + 1], q2 = upv[nc + 2], q3 = upv[nc + 3];
    #pragma unroll 2
    for (int tb = nc; tb < T_STEPS; tb += 4) {
        const int nb = (tb + 4 < T_STEPS) ? tb + 4 : T_STEPS - 4;  // tail clamp (dead)
        float4 n0 = upv[nb];
        float4 n1 = upv[nb + 1];
        float4 n2 = upv[nb + 2];
        float4 n3 = upv[nb + 3];
        step(q0, tb);
        step(q1, tb + 1);
        step(q2, tb + 2);
        step(q3, tb + 3);
        q0 = n0; q1 = n1; q2 = n2; q3 = n3;
    }
}

extern "C" void kernel_launch(void* const* d_in, const int* in_sizes, int n_in,
                              void* d_out, int out_size, void* d_ws, size_t ws_size,
                              hipStream_t stream) {
    const float* u   = (const float*)d_in[0];
    const float* Wih = (const float*)d_in[1];
    const float* Whh = (const float*)d_in[2];
    const float* bih = (const float*)d_in[3];
    const float* bhh = (const float*)d_in[4];
    const float* Whr = (const float*)d_in[5];
    const int*   ncp = (const int*)d_in[6];
    float* out = (float*)d_out;

    const int B = in_sizes[0] / (T_STEPS * 4);  // u_train is (B, T, 4)
    const int blocks = (B + SEQS_PER_BLOCK - 1) / SEQS_PER_BLOCK;

    // workspace: c handoff [B][16] then h handoff [B][2]
    float* ws_c = (float*)d_ws;
    float* ws_h = ws_c + (size_t)B * 16;

    hipLaunchKernelGGL(lstm_phase1_kernel, dim3(blocks), dim3(256), 0, stream,
                       u, Wih, Whh, bih, bhh, Whr, ncp, out, ws_c, ws_h, B);
    hipLaunchKernelGGL(lstm_phase2_kernel, dim3(blocks), dim3(256), 0, stream,
                       u, Wih, Whh, bih, bhh, Whr, ncp, out, ws_c, ws_h, B);
}